// Round 1
// baseline (242.412 us; speedup 1.0000x reference)
//
#include <hip/hip_runtime.h>

// Problem constants (from reference setup_inputs)
#define Bn 16
#define Yn 32
#define Hn 256
#define Wn 256
#define HWn (Hn * Wn)          // 65536
#define NPIX (Bn * HWn)        // 1,048,576 pixels
#define DIST_IND_F 7.0f

// Per-pixel scale: loss/Y then mean over B*H*W -> 1/(Y*NPIX) = 2^-25 (exact)
#define OUT_SCALE (1.0f / ((float)Yn * (float)NPIX))

// 2 pixels (float2) per thread -> NPIX/2 threads -> 2048 blocks of 256.
// 2048 blocks = 8 blocks/CU; with <=64 VGPR (launch_bounds(256,8)) the whole
// grid is resident at 32 waves/CU (8 waves/SIMD) -- double the prior occupancy.
#define NBLK (NPIX / 2 / 256)  // 2048

__device__ __forceinline__ void regress_f(float n, float sx, float sxx,
                                          float sy, float sxy,
                                          float& slope, float& inter, bool& valid) {
    valid = (n >= 3.0f);
    float n_safe = fmaxf(n, 1.0f);
    float cov = sxy - sx * sy / n_safe;
    float var = sxx - sx * sx / n_safe;
    float var_safe = (var > 0.0f) ? var : 1.0f;
    float s = cov / var_safe;
    s = fminf(fmaxf(s, 0.0f), 2.0f);   // clip [SLOPE_MIN, SLOPE_MAX]
    slope = s;
    inter = (sy - s * sx) / n_safe;
}

// Streaming formulation (identical arithmetic to the verified 244.5us kernel,
// just 2 pixels/thread instead of 4): one pass over y maintaining running
// sufficient statistics (Sv, St*v, Sv^2) per pixel; on each new strict
// diff-minimum, snapshot the prefix sums (these ARE the "before"-segment sums
// since mb = t < idx). Residual SSE in closed form.
//
// CHANGES vs prior round:
//  1. NO global atomicAdd. 1024+ same-address device-scope atomics from 8
//     non-coherent XCDs serialize at the coherence point; suspected ~200us
//     tail. Each block stores its partial to d_ws; a 1-block reducer sums.
//  2. float2/thread, chunk=4 double-buffer: ~50 VGPR -> 8 waves/SIMD.
__global__ __launch_bounds__(256, 8)
void drl_main(const float* __restrict__ out, float* __restrict__ partial) {
    const int g = blockIdx.x * 256 + threadIdx.x;     // float2-group id
    const int b = g >> 15;                            // / (HWn/2)
    const int hw2 = g & ((HWn / 2) - 1);              // float2 index in image
    const float2* base = (const float2*)(out + (size_t)b * (Yn * HWn)) + hw2;
    const size_t stride = HWn / 2;                    // float2 stride per y

    float vprev[2], dmin[2], s1[2], sx1[2], svv[2], s1b[2], sxb[2], svvb[2];
    int idx[2];
#pragma unroll
    for (int c = 0; c < 2; ++c) {
        vprev[c] = 0.0f; dmin[c] = -DIST_IND_F;
        s1[c] = 0.0f; sx1[c] = 0.0f; svv[c] = 0.0f;
        s1b[c] = 0.0f; sxb[c] = 0.0f; svvb[c] = 0.0f;
        idx[c] = 0;
    }

    // 2-deep chunk pipeline: load chunk k+1 (4 planes) while processing chunk k.
    float2 buf[2][4];
#pragma unroll
    for (int j = 0; j < 4; ++j) buf[0][j] = base[(size_t)j * stride];

#pragma unroll
    for (int k = 0; k < 8; ++k) {
        if (k < 7) {
#pragma unroll
            for (int j = 0; j < 4; ++j)
                buf[(k + 1) & 1][j] = base[(size_t)((k + 1) * 4 + j) * stride];
        }
#pragma unroll
        for (int j = 0; j < 4; ++j) {
            const int t = k * 4 + j;                  // compile-time constant
            const float tf = (float)t;
            float2 vv = buf[k & 1][j];
            float vc[2] = {vv.x, vv.y};
#pragma unroll
            for (int c = 0; c < 2; ++c) {
                float v = vc[c];
                if (t >= 2 && t <= 30) {              // diff check window
                    float d = v - vprev[c];           // same fp32 diff as ref
                    if (d < dmin[c]) {                // strict < : first argmin
                        dmin[c] = d; idx[c] = t;
                        s1b[c] = s1[c];               // prefix sums over t' < t
                        sxb[c] = sx1[c];
                        svvb[c] = svv[c];
                    }
                }
                s1[c] += v;
                sx1[c] = fmaf(tf, v, sx1[c]);
                svv[c] = fmaf(v, v, svv[c]);
                vprev[c] = v;
            }
        }
    }

    // Epilogue: closed-form regressions + residuals per pixel
    float loss = 0.0f;
#pragma unroll
    for (int c = 0; c < 2; ++c) {
        const int nb = idx[c];
        const int na = Yn - nb;
        const float fnb = (float)nb, fna = (float)na;
        const float sx_b  = (float)((nb * (nb - 1)) / 2);
        const float sxx_b = (float)(((nb - 1) * nb * (2 * nb - 1)) / 6);
        const float sx_a  = (float)((na * (na - 1)) / 2);
        const float sxx_a = (float)(((na - 1) * na * (2 * na - 1)) / 6);

        const float sy_b  = s1b[c];
        const float sxy_b = sxb[c];
        const float svv_b = svvb[c];
        const float sy_a  = s1[c] - sy_b;
        const float sxy_a = (sx1[c] - sxb[c]) - fnb * sy_a;  // x = t - idx
        const float svv_a = svv[c] - svv_b;

        float slope_b, int_b, slope_a, int_a;
        bool val_b, val_a;
        regress_f(fnb, sx_b, sxx_b, sy_b, sxy_b, slope_b, int_b, val_b);
        regress_f(fna, sx_a, sxx_a, sy_a, sxy_a, slope_a, int_a, val_a);

        float res_b = svv_b - 2.0f * slope_b * sxy_b - 2.0f * int_b * sy_b
                    + slope_b * slope_b * sxx_b
                    + 2.0f * slope_b * int_b * sx_b
                    + int_b * int_b * fnb;
        float res_a = svv_a - 2.0f * slope_a * sxy_a - 2.0f * int_a * sy_a
                    + slope_a * slope_a * sxx_a
                    + 2.0f * slope_a * int_a * sx_a
                    + int_a * int_a * fna;

        loss += (val_b ? res_b : 0.0f) + (val_a ? res_a : 0.0f);
    }

    // Block reduction: wave shuffle (64 lanes) -> LDS (4 waves) -> 1 store/block
#pragma unroll
    for (int off = 32; off > 0; off >>= 1)
        loss += __shfl_down(loss, off, 64);

    __shared__ float smem[4];
    const int lane = threadIdx.x & 63;
    const int wid  = threadIdx.x >> 6;
    if (lane == 0) smem[wid] = loss;
    __syncthreads();
    if (threadIdx.x == 0)
        partial[blockIdx.x] = smem[0] + smem[1] + smem[2] + smem[3];
}

// Second pass: sum NBLK (=2048) partials in one block. Replaces the contended
// same-address atomicAdd tail (1024 cross-XCD serialized atomics suspected as
// the dominant cost of the 244.5us baseline).
__global__ __launch_bounds__(256)
void drl_reduce(const float* __restrict__ partial, float* __restrict__ loss_out) {
    const float4* p4 = (const float4*)partial;        // 2048 floats = 512 float4
    float4 a = p4[threadIdx.x];
    float4 b = p4[threadIdx.x + 256];
    float s = a.x + a.y + a.z + a.w + b.x + b.y + b.z + b.w;
#pragma unroll
    for (int off = 32; off > 0; off >>= 1)
        s += __shfl_down(s, off, 64);

    __shared__ float smem[4];
    const int lane = threadIdx.x & 63;
    const int wid  = threadIdx.x >> 6;
    if (lane == 0) smem[wid] = s;
    __syncthreads();
    if (threadIdx.x == 0)
        loss_out[0] = (smem[0] + smem[1] + smem[2] + smem[3]) * OUT_SCALE;
}

extern "C" void kernel_launch(void* const* d_in, const int* in_sizes, int n_in,
                              void* d_out, int out_size, void* d_ws, size_t ws_size,
                              hipStream_t stream) {
    const float* out_in = (const float*)d_in[0];   // 'out'; 'target' (d_in[1]) unused
    float* loss = (float*)d_out;
    float* partial = (float*)d_ws;                 // needs NBLK*4 = 8 KiB of ws

    // d_out is poisoned 0xAA before every launch; reducer writes [0], zero the
    // rest for identical output semantics to the prior verified kernel.
    hipMemsetAsync(loss, 0, sizeof(float) * (size_t)out_size, stream);

    dim3 block(256);
    drl_main<<<dim3(NBLK), block, 0, stream>>>(out_in, partial);
    drl_reduce<<<dim3(1), block, 0, stream>>>(partial, loss);
}